// Round 1
// baseline (1789.811 us; speedup 1.0000x reference)
//
#include <hip/hip_runtime.h>
#include <cstdint>
#include <cstddef>

#define BATCH 32
#define IMH 512
#define IMW 512
#define KMAX 256
#define CAP 65536   // per-image candidate capacity (expected ~29k local maxima)

__device__ __forceinline__ float sigmoidf_(float x) {
    return 1.0f / (1.0f + expf(-x));
}

// ---------------------------------------------------------------------------
// Kernel 1: fused score computation + 3x3 NMS + candidate compaction.
// Block = 32x8 threads; LDS tile holds scores with a 1-px halo (-inf outside).
// Candidate key = (score_bits << 32) | ~pixel_index  -> unsigned descending
// order == (score desc, index asc), matching lax.top_k stable tie-break.
// ---------------------------------------------------------------------------
__global__ __launch_bounds__(256)
void score_nms_kernel(const float* __restrict__ route,
                      const float* __restrict__ unc,
                      unsigned long long* __restrict__ cand,
                      int* __restrict__ cnt) {
    const int b  = blockIdx.z;
    const int bx = blockIdx.x * 32;
    const int by = blockIdx.y * 8;
    __shared__ float sc[10][34];

    const int tid = threadIdx.y * 32 + threadIdx.x;
    const float* rB = route + (size_t)b * IMH * IMW;
    const float* uB = unc   + (size_t)b * IMH * IMW;

    // Fill 10x34 halo tile (340 cells) with scores; -inf outside image
    for (int i = tid; i < 340; i += 256) {
        const int hy = i / 34, hx = i % 34;
        const int gy = by + hy - 1, gx = bx + hx - 1;
        float s = -INFINITY;
        if (gy >= 0 && gy < IMH && gx >= 0 && gx < IMW) {
            const float r = rB[gy * IMW + gx];
            const float u = uB[gy * IMW + gx];
            const float sg = sigmoidf_(r);
            s = sg * sg * (1.0f - 0.35f * sigmoidf_(u));
        }
        sc[hy][hx] = s;
    }
    __syncthreads();

    const int ty = threadIdx.y, tx = threadIdx.x;
    const float s = sc[ty + 1][tx + 1];
    float m;
    m = sc[ty][tx];
    m = fmaxf(m, sc[ty][tx + 1]);
    m = fmaxf(m, sc[ty][tx + 2]);
    m = fmaxf(m, sc[ty + 1][tx]);
    m = fmaxf(m, sc[ty + 1][tx + 2]);
    m = fmaxf(m, sc[ty + 2][tx]);
    m = fmaxf(m, sc[ty + 2][tx + 1]);
    m = fmaxf(m, sc[ty + 2][tx + 2]);

    if (s >= m) {   // s == maxpool3x3(s)  <=>  s >= all 8 neighbors
        const unsigned int idx = (unsigned)((by + ty) * IMW + (bx + tx));
        const unsigned int sb  = __float_as_uint(s);   // s > 0 -> bits ordered
        const unsigned long long key =
            ((unsigned long long)sb << 32) | (unsigned int)(~idx);
        const int pos = atomicAdd(&cnt[b], 1);
        if (pos < CAP) cand[(size_t)b * CAP + pos] = key;
    }
}

// ---------------------------------------------------------------------------
// Kernel 2: one block (256 threads) per image. Exact top-256 by 64-bit key via
// nibble radix-select, then collect + bitonic sort descending + ROI epilogue.
// ---------------------------------------------------------------------------
__global__ __launch_bounds__(256)
void topk_rois_kernel(const unsigned long long* __restrict__ cand,
                      const int* __restrict__ cnt,
                      const float* __restrict__ scale,
                      const float* __restrict__ unc,
                      const int* __restrict__ imh,
                      const int* __restrict__ imw,
                      float* __restrict__ rois,
                      float* __restrict__ scoresOut,
                      float* __restrict__ validOut) {
    const int b   = blockIdx.x;
    const int tid = threadIdx.x;

    int n = cnt[b];
    if (n > CAP) n = CAP;
    const unsigned long long* cb = cand + (size_t)b * CAP;

    __shared__ unsigned int hist[16];
    __shared__ unsigned long long prefix_s;
    __shared__ int remk_s;
    __shared__ unsigned long long sel[KMAX];
    __shared__ int c2;

    unsigned long long T = 0;   // n <= KMAX: collect everything

    if (n > KMAX) {
        if (tid == 0) { prefix_s = 0; remk_s = KMAX; }
        __syncthreads();
        for (int p = 15; p >= 0; --p) {
            if (tid < 16) hist[tid] = 0;
            __syncthreads();
            const unsigned long long pre = prefix_s;
            for (int i = tid; i < n; i += 256) {
                const unsigned long long k = cb[i];
                const bool ok = (p == 15) || ((k >> ((p + 1) * 4)) == pre);
                if (ok) atomicAdd(&hist[(unsigned)(k >> (p * 4)) & 15u], 1u);
            }
            __syncthreads();
            if (tid == 0) {
                int rem = remk_s;
                int v;
                for (v = 15; v >= 0; --v) {
                    const int hv = (int)hist[v];
                    if (rem <= hv) break;
                    rem -= hv;
                }
                if (v < 0) v = 0;   // safety; invariant keeps this unreachable
                prefix_s = (pre << 4) | (unsigned)v;
                remk_s = rem;
            }
            __syncthreads();
        }
        T = prefix_s;   // exact key of the 256th-largest (keys unique)
    }

    // Collect the top-256 keys (order arbitrary here)
    if (tid == 0) c2 = 0;
    sel[tid] = 0ull;
    __syncthreads();
    for (int i = tid; i < n; i += 256) {
        const unsigned long long k = cb[i];
        if (k >= T && k != 0ull) {
            const int pos = atomicAdd(&c2, 1);
            if (pos < KMAX) sel[pos] = k;
        }
    }
    __syncthreads();

    // Bitonic sort descending (keys unique; zeros sink to the end)
    for (int kk = 2; kk <= KMAX; kk <<= 1) {
        for (int j = kk >> 1; j > 0; j >>= 1) {
            const int ixj = tid ^ j;
            if (ixj > tid) {
                const unsigned long long a  = sel[tid];
                const unsigned long long bb = sel[ixj];
                const bool desc = ((tid & kk) == 0);
                if (desc ? (a < bb) : (a > bb)) {
                    sel[tid] = bb;
                    sel[ixj] = a;
                }
            }
            __syncthreads();
        }
    }

    // Epilogue: decode key -> (value, y, x); gather scale/unc; write outputs
    const unsigned long long k = sel[tid];
    const float value = __uint_as_float((unsigned)(k >> 32));
    const bool valid  = (k != 0ull) && (value > 0.0f);

    float r0 = 0.f, r1 = 0.f, r2 = 0.f, r3 = 0.f, r4 = 0.f, sv = 0.f, vv = 0.f;
    if (valid) {
        const unsigned idx = ~(unsigned)(k & 0xFFFFFFFFull);
        const int y = (int)(idx / IMW);
        const int x = (int)(idx % IMW);
        const float cx = ((float)x + 0.5f) * 4.0f;
        const float cy = ((float)y + 0.5f) * 4.0f;
        const float sg = scale[(size_t)b * IMH * IMW + idx];
        const float uu = unc[(size_t)b * IMH * IMW + idx];
        const float su = sigmoidf_(uu);
        float side = 32.0f + sigmoidf_(sg) * (512.0f - 32.0f);
        side = side * (1.0f + 0.25f * su);
        const float half = side * 0.5f;
        const float fw = (float)imw[0];
        const float fh = (float)imh[0];
        r0 = (float)b;
        r1 = fminf(fmaxf(cx - half, 0.0f), fw - 1.0f);
        r2 = fminf(fmaxf(cy - half, 0.0f), fh - 1.0f);
        r3 = fminf(fmaxf(cx + half, 1.0f), fw);
        r4 = fminf(fmaxf(cy + half, 1.0f), fh);
        sv = value;
        vv = 1.0f;
    }
    float* roiP = rois + ((size_t)b * KMAX + tid) * 5;
    roiP[0] = r0; roiP[1] = r1; roiP[2] = r2; roiP[3] = r3; roiP[4] = r4;
    scoresOut[b * KMAX + tid] = sv;
    validOut[b * KMAX + tid]  = vv;
}

extern "C" void kernel_launch(void* const* d_in, const int* in_sizes, int n_in,
                              void* d_out, int out_size, void* d_ws, size_t ws_size,
                              hipStream_t stream) {
    const float* route = (const float*)d_in[0];
    const float* scale = (const float*)d_in[1];
    const float* unc   = (const float*)d_in[2];
    const int*   imh   = (const int*)d_in[3];
    const int*   imw   = (const int*)d_in[4];

    unsigned long long* cand = (unsigned long long*)d_ws;
    int* cnt = (int*)((char*)d_ws + (size_t)BATCH * CAP * sizeof(unsigned long long));

    float* rois      = (float*)d_out;                       // [B, 256, 5]
    float* scoresOut = rois + (size_t)BATCH * KMAX * 5;     // [B, 256]
    float* validOut  = scoresOut + (size_t)BATCH * KMAX;    // [B, 256]

    hipMemsetAsync(cnt, 0, BATCH * sizeof(int), stream);

    dim3 grid1(IMW / 32, IMH / 8, BATCH);
    dim3 blk1(32, 8, 1);
    score_nms_kernel<<<grid1, blk1, 0, stream>>>(route, unc, cand, cnt);

    topk_rois_kernel<<<BATCH, 256, 0, stream>>>(cand, cnt, scale, unc,
                                                imh, imw, rois, scoresOut, validOut);
}

// Round 2
// 140.777 us; speedup vs baseline: 12.7138x; 12.7138x over previous
//
#include <hip/hip_runtime.h>
#include <cstdint>
#include <cstddef>

#define BATCH 32
#define IMH 512
#define IMW 512
#define KMAX 256
#define CAP 65536        // per-image candidate capacity (expected ~29k local maxima)

// K1 tiling: 64x32 pixels per 256-thread block, 8 rows per thread
#define TW 64
#define TH 32
#define LCAP 2048        // per-block LDS candidate cap (expected ~230)

// K2 histogram
#define NBINS 8192       // top 13 bits of the 64-bit key
#define SURV_CAP 4096

typedef unsigned long long u64;

__device__ __forceinline__ float sigmoidf_(float x) {
    return 1.0f / (1.0f + expf(-x));
}

// ---------------------------------------------------------------------------
// Kernel 1: fused score + 3x3 NMS + per-block candidate aggregation.
// Candidate key = (score_bits << 32) | ~pixel_index  -> unsigned descending
// order == (score desc, index asc), matching lax.top_k stable tie-break.
// One global atomic per BLOCK (not per candidate).
// ---------------------------------------------------------------------------
__global__ __launch_bounds__(256)
void score_nms_kernel(const float* __restrict__ route,
                      const float* __restrict__ unc,
                      u64* __restrict__ cand,
                      int* __restrict__ cnt) {
    const int b  = blockIdx.z;
    const int bx = blockIdx.x * TW;
    const int by = blockIdx.y * TH;

    __shared__ float sc[TH + 2][TW + 2];   // 34 x 66 floats
    __shared__ u64 lcand[LCAP];
    __shared__ int lcnt;
    __shared__ int gbase;

    const int tid = threadIdx.x;
    if (tid == 0) lcnt = 0;

    const float* rB = route + (size_t)b * IMH * IMW;
    const float* uB = unc   + (size_t)b * IMH * IMW;

    // Fill halo tile (34*66 = 2244 cells); -inf outside image
    for (int i = tid; i < (TH + 2) * (TW + 2); i += 256) {
        const int hy = i / (TW + 2), hx = i % (TW + 2);
        const int gy = by + hy - 1, gx = bx + hx - 1;
        float s = -INFINITY;
        if (gy >= 0 && gy < IMH && gx >= 0 && gx < IMW) {
            const float r = rB[gy * IMW + gx];
            const float u = uB[gy * IMW + gx];
            const float sg = sigmoidf_(r);
            s = sg * sg * (1.0f - 0.35f * sigmoidf_(u));
        }
        sc[hy][hx] = s;
    }
    __syncthreads();

    // Each thread: column tx, rows [ty0, ty0+8). s == maxpool3x3(s) <=> s >= max9.
    const int tx  = tid & 63;
    const int ty0 = (tid >> 6) * 8;

    float cm[11];                      // column-triple max for rows ty0-1 .. ty0+9
    #pragma unroll
    for (int r = 0; r < 11; ++r) {
        const int y = ty0 + r;         // halo row index ty0+r corresponds to sc[y][*]
        cm[r] = fmaxf(fmaxf(sc[y][tx], sc[y][tx + 1]), sc[y][tx + 2]);
    }
    #pragma unroll
    for (int r = 0; r < 8; ++r) {
        const float s  = sc[ty0 + r + 1][tx + 1];
        const float m9 = fmaxf(fmaxf(cm[r], cm[r + 1]), cm[r + 2]);
        if (s >= m9) {
            const unsigned idx = (unsigned)((by + ty0 + r) * IMW + (bx + tx));
            const u64 key = ((u64)__float_as_uint(s) << 32) | (unsigned)(~idx);
            const int pos = atomicAdd(&lcnt, 1);
            if (pos < LCAP) lcand[pos] = key;
        }
    }
    __syncthreads();

    const int m = (lcnt < LCAP) ? lcnt : LCAP;
    if (tid == 0) gbase = atomicAdd(&cnt[b], m);
    __syncthreads();
    const int base = gbase;
    for (int i = tid; i < m; i += 256) {
        const int p = base + i;
        if (p < CAP) cand[(size_t)b * CAP + p] = lcand[i];
    }
}

// ---------------------------------------------------------------------------
// Kernel 2: one block per image. Exact top-256:
//   scan 1: 8192-bin histogram on top-13 key bits -> threshold bin (exact)
//   scan 2: compact keys above bin (into sel) and in-bin survivors (into LDS)
//   tiny nibble radix-select among survivors -> exact 256th key
//   bitonic sort 256 desc -> ROI epilogue
// ---------------------------------------------------------------------------
__global__ __launch_bounds__(256)
void topk_rois_kernel(const u64* __restrict__ cand,
                      const int* __restrict__ cnt,
                      const float* __restrict__ scale,
                      const float* __restrict__ unc,
                      const int* __restrict__ imh,
                      const int* __restrict__ imw,
                      float* __restrict__ rois,
                      float* __restrict__ scoresOut,
                      float* __restrict__ validOut) {
    const int b   = blockIdx.x;
    const int tid = threadIdx.x;

    int n = cnt[b];
    if (n > CAP) n = CAP;
    const u64* cb = cand + (size_t)b * CAP;

    __shared__ unsigned int hist[NBINS];          // 32 KB; reused as surv[] later
    u64* surv = (u64*)hist;                       // SURV_CAP u64 = same 32 KB
    __shared__ u64 sel[KMAX];
    __shared__ unsigned int ts[256];
    __shared__ unsigned int suf[256];
    __shared__ int chunkS, binStarS, aboveS, remkS;
    __shared__ int cTop, cSurv;
    __shared__ u64 prefS;
    __shared__ int rem2S;
    __shared__ unsigned int h2[16];

    sel[tid] = 0ull;
    if (tid == 0) { cTop = 0; cSurv = 0; }
    __syncthreads();

    if (n > KMAX) {
        // ---- scan 1: histogram on top 13 bits ----
        for (int i = tid; i < NBINS; i += 256) hist[i] = 0;
        __syncthreads();
        for (int i = tid; i < n; i += 256)
            atomicAdd(&hist[(unsigned)(cb[i] >> 51)], 1u);
        __syncthreads();

        unsigned s = 0;
        #pragma unroll
        for (int j = 0; j < 32; ++j) s += hist[tid * 32 + j];
        ts[tid] = s;
        __syncthreads();
        if (tid == 0) {
            unsigned acc = 0;
            for (int t = 255; t >= 0; --t) { suf[t] = acc; acc += ts[t]; }
        }
        __syncthreads();
        if (suf[tid] < (unsigned)KMAX && suf[tid] + ts[tid] >= (unsigned)KMAX)
            chunkS = tid;
        __syncthreads();
        if (tid == 0) {
            const int t = chunkS;
            unsigned acc = suf[t];
            int bbin = t * 32 + 31;
            for (; bbin >= t * 32; --bbin) {
                const unsigned h = hist[bbin];
                if (acc + h >= (unsigned)KMAX) break;
                acc += h;
            }
            binStarS = bbin;
            aboveS   = (int)acc;           // keys in bins strictly above (< 256)
            remkS    = KMAX - (int)acc;    // how many to take from bin*
        }
        __syncthreads();
        const unsigned bstar = (unsigned)binStarS;
        const int remk = remkS;
        __syncthreads();   // everyone has bstar before hist is overwritten

        // ---- scan 2: compact ----
        for (int i = tid; i < n; i += 256) {
            const u64 k = cb[i];
            const unsigned bin = (unsigned)(k >> 51);
            if (bin > bstar) {
                const int p = atomicAdd(&cTop, 1);
                if (p < KMAX) sel[p] = k;
            } else if (bin == bstar) {
                const int p = atomicAdd(&cSurv, 1);
                if (p < SURV_CAP) surv[p] = k;   // overwrites hist (no longer needed)
            }
        }
        __syncthreads();
        const int ns = (cSurv < SURV_CAP) ? cSurv : SURV_CAP;

        // ---- nibble radix-select: remk-th largest among survivors ----
        // survivors share key bits [63:51]; select over nibbles 12..0
        if (tid == 0) { prefS = (u64)(bstar >> 1); rem2S = remk; }
        __syncthreads();
        for (int p = 12; p >= 0; --p) {
            if (tid < 16) h2[tid] = 0;
            __syncthreads();
            const u64 pre = prefS;
            for (int i = tid; i < ns; i += 256) {
                const u64 k = surv[i];
                if ((k >> ((p + 1) * 4)) == pre)
                    atomicAdd(&h2[(unsigned)(k >> (p * 4)) & 15u], 1u);
            }
            __syncthreads();
            if (tid == 0) {
                int rem = rem2S;
                int v;
                for (v = 15; v >= 0; --v) {
                    const int hv = (int)h2[v];
                    if (rem <= hv) break;
                    rem -= hv;
                }
                if (v < 0) v = 0;
                prefS = (pre << 4) | (unsigned)v;
                rem2S = rem;
            }
            __syncthreads();
        }
        const u64 T = prefS;

        // collect survivors >= T (exactly remk of them; keys unique)
        for (int i = tid; i < ns; i += 256) {
            const u64 k = surv[i];
            if (k >= T) {
                const int p = atomicAdd(&cTop, 1);
                if (p < KMAX) sel[p] = k;
            }
        }
        __syncthreads();
    } else {
        for (int i = tid; i < n; i += 256) {
            const int p = atomicAdd(&cTop, 1);
            sel[p] = cb[i];
        }
        __syncthreads();
    }

    // ---- bitonic sort descending (keys unique; zeros sink) ----
    for (int kk = 2; kk <= KMAX; kk <<= 1) {
        for (int j = kk >> 1; j > 0; j >>= 1) {
            const int ixj = tid ^ j;
            if (ixj > tid) {
                const u64 a  = sel[tid];
                const u64 bb = sel[ixj];
                const bool desc = ((tid & kk) == 0);
                if (desc ? (a < bb) : (a > bb)) {
                    sel[tid] = bb;
                    sel[ixj] = a;
                }
            }
            __syncthreads();
        }
    }

    // ---- epilogue ----
    const u64 k = sel[tid];
    const float value = __uint_as_float((unsigned)(k >> 32));
    const bool valid  = (k != 0ull) && (value > 0.0f);

    float r0 = 0.f, r1 = 0.f, r2 = 0.f, r3 = 0.f, r4 = 0.f, sv = 0.f, vv = 0.f;
    if (valid) {
        const unsigned idx = ~(unsigned)(k & 0xFFFFFFFFull);
        const int y = (int)(idx / IMW);
        const int x = (int)(idx % IMW);
        const float cx = ((float)x + 0.5f) * 4.0f;
        const float cy = ((float)y + 0.5f) * 4.0f;
        const float sg = scale[(size_t)b * IMH * IMW + idx];
        const float uu = unc[(size_t)b * IMH * IMW + idx];
        const float su = sigmoidf_(uu);
        float side = 32.0f + sigmoidf_(sg) * (512.0f - 32.0f);
        side = side * (1.0f + 0.25f * su);
        const float half = side * 0.5f;
        const float fw = (float)imw[0];
        const float fh = (float)imh[0];
        r0 = (float)b;
        r1 = fminf(fmaxf(cx - half, 0.0f), fw - 1.0f);
        r2 = fminf(fmaxf(cy - half, 0.0f), fh - 1.0f);
        r3 = fminf(fmaxf(cx + half, 1.0f), fw);
        r4 = fminf(fmaxf(cy + half, 1.0f), fh);
        sv = value;
        vv = 1.0f;
    }
    float* roiP = rois + ((size_t)b * KMAX + tid) * 5;
    roiP[0] = r0; roiP[1] = r1; roiP[2] = r2; roiP[3] = r3; roiP[4] = r4;
    scoresOut[b * KMAX + tid] = sv;
    validOut[b * KMAX + tid]  = vv;
}

extern "C" void kernel_launch(void* const* d_in, const int* in_sizes, int n_in,
                              void* d_out, int out_size, void* d_ws, size_t ws_size,
                              hipStream_t stream) {
    const float* route = (const float*)d_in[0];
    const float* scale = (const float*)d_in[1];
    const float* unc   = (const float*)d_in[2];
    const int*   imh   = (const int*)d_in[3];
    const int*   imw   = (const int*)d_in[4];

    u64* cand = (u64*)d_ws;
    int* cnt  = (int*)((char*)d_ws + (size_t)BATCH * CAP * sizeof(u64));

    float* rois      = (float*)d_out;                       // [B, 256, 5]
    float* scoresOut = rois + (size_t)BATCH * KMAX * 5;     // [B, 256]
    float* validOut  = scoresOut + (size_t)BATCH * KMAX;    // [B, 256]

    hipMemsetAsync(cnt, 0, BATCH * sizeof(int), stream);

    dim3 grid1(IMW / TW, IMH / TH, BATCH);
    score_nms_kernel<<<grid1, 256, 0, stream>>>(route, unc, cand, cnt);

    topk_rois_kernel<<<BATCH, 256, 0, stream>>>(cand, cnt, scale, unc,
                                                imh, imw, rois, scoresOut, validOut);
}